// Round 8
// baseline (321.015 us; speedup 1.0000x reference)
//
#include <hip/hip_runtime.h>

#define EPS_F 0.1f
#define A_F 100.0f
#define NUMNEG_F 10.0f
#define EXP_EPS 1.1051709f   // e^0.1; gate: dist<EPS  <=>  (-inner + s) < e^EPS
#define BATCH 16
#define NBLOCKS 4096
// meta packing: meta = excl_offset | (deg << 20). Requires E < 2^20 (E=1e6 OK)
// and deg < 4096 (deg ~ Poisson(10), max ~31).

// ---- K1: zero d_out + histogram + record per-edge slot (coalesced) ----
__global__ __launch_bounds__(256) void hist_kernel(
    const int* __restrict__ u_idx,
    int* __restrict__ counts, int* __restrict__ slot,
    float* __restrict__ out, int out_n, int E)
{
    const int tid = blockIdx.x * blockDim.x + threadIdx.x;
    const int nth = gridDim.x * blockDim.x;

    // zero d_out (grad accumulated by atomics; energy overwritten by reduce)
    float4* o4 = (float4*)out;
    const int n4 = out_n >> 2;
    for (int i = tid; i < n4; i += nth) o4[i] = float4{0.f, 0.f, 0.f, 0.f};
    if (tid == 0)
        for (int i = n4 * 4; i < out_n; i++) out[i] = 0.f;

    for (int e = tid; e < E; e += nth)
        slot[e] = atomicAdd(&counts[u_idx[e]], 1);   // slot write is streaming
}

// ---- K2a: per-256-chunk sums of counts ----
__global__ __launch_bounds__(256) void scan_partial_kernel(
    const int* __restrict__ counts, int* __restrict__ partials, int N)
{
    __shared__ int lds[256];
    const int i = blockIdx.x * 256 + threadIdx.x;
    lds[threadIdx.x] = (i < N) ? counts[i] : 0;
    __syncthreads();
    for (int off = 128; off >= 1; off >>= 1) {
        if (threadIdx.x < off) lds[threadIdx.x] += lds[threadIdx.x + off];
        __syncthreads();
    }
    if (threadIdx.x == 0) partials[blockIdx.x] = lds[0];
}

// ---- K2b: exclusive scan of partials in-place (one wave, chunked) ----
__global__ __launch_bounds__(64) void scan_bases_kernel(
    int* __restrict__ partials, int nb)
{
    const int lane = threadIdx.x;
    int carry = 0;
    for (int base = 0; base < nb; base += 64) {
        const int i = base + lane;
        const int orig = (i < nb) ? partials[i] : 0;
        int v = orig;
        #pragma unroll
        for (int off = 1; off < 64; off <<= 1) {
            const int t = __shfl_up(v, off, 64);
            if (lane >= off) v += t;
        }
        if (i < nb) partials[i] = carry + v - orig;   // exclusive
        carry += __shfl(v, 63, 64);                   // chunk total
    }
}

// ---- K2c: per-chunk exclusive scan + pack meta = offset | (deg<<20) ----
__global__ __launch_bounds__(256) void scan_meta_kernel(
    const int* __restrict__ counts, const int* __restrict__ bases,
    int* __restrict__ meta, int N)
{
    __shared__ int lds[256];
    const int t = threadIdx.x;
    const int i = blockIdx.x * 256 + t;
    const int deg = (i < N) ? counts[i] : 0;
    lds[t] = deg;
    __syncthreads();
    for (int off = 1; off < 256; off <<= 1) {       // Hillis-Steele inclusive
        const int add = (t >= off) ? lds[t - off] : 0;
        __syncthreads();
        lds[t] += add;
        __syncthreads();
    }
    if (i < N) {
        const int excl = lds[t] - deg + bases[blockIdx.x];
        meta[i] = excl | (deg << 20);
    }
}

// ---- K3: atomic-free CSR scatter (offsets gather is L2/L3-hot, 400 KB) ----
__global__ __launch_bounds__(256) void scatter_kernel(
    const int* __restrict__ u_idx, const int* __restrict__ v_idx,
    const int* __restrict__ slot, const int* __restrict__ meta,
    int* __restrict__ adj, int E)
{
    const int tid = blockIdx.x * blockDim.x + threadIdx.x;
    const int nth = gridDim.x * blockDim.x;
    for (int e = tid; e < E; e += nth)
        adj[(meta[u_idx[e]] & 0xFFFFF) + slot[e]] = v_idx[e];
}

// fold-merge: reduce two edges' partial-product vectors one level.
__device__ __forceinline__ float red2(float a, float b, int dist, bool sel) {
    const float fa = a + __shfl_xor(a, dist, 64);
    const float fb = b + __shfl_xor(b, dist, 64);
    return sel ? fb : fa;
}

// 16-edge transpose-reduce + lane-parallel epilogue + scatter.
#define PROCESS_BATCH(xuj, vs, xv, bn, gacc)                                   \
    do {                                                                       \
        float p[BATCH];                                                        \
        _Pragma("unroll")                                                      \
        for (int k = 0; k < BATCH; k++) p[k] = (xuj) * (xv)[k];                \
        float q0 = red2(p[0], p[8],  32, m32);                                 \
        float q1 = red2(p[1], p[9],  32, m32);                                 \
        float q2 = red2(p[2], p[10], 32, m32);                                 \
        float q3 = red2(p[3], p[11], 32, m32);                                 \
        float q4 = red2(p[4], p[12], 32, m32);                                 \
        float q5 = red2(p[5], p[13], 32, m32);                                 \
        float q6 = red2(p[6], p[14], 32, m32);                                 \
        float q7 = red2(p[7], p[15], 32, m32);                                 \
        float r0 = red2(q0, q4, 16, m16);                                      \
        float r1 = red2(q1, q5, 16, m16);                                      \
        float r2 = red2(q2, q6, 16, m16);                                      \
        float r3 = red2(q3, q7, 16, m16);                                      \
        float s0 = red2(r0, r2, 8, m8);                                        \
        float s1 = red2(r1, r3, 8, m8);                                        \
        float t0 = red2(s0, s1, 4, m4);                                        \
        t0 += __shfl_xor(t0, 2, 64);                                           \
        t0 += __shfl_xor(t0, 1, 64);                                           \
        const float inner = fminf(t0, -1.0f - 1e-7f);                          \
        const float sq    = __builtin_amdgcn_sqrtf(fmaf(inner, inner, -1.0f)); \
        const float tt    = sq - inner;                                        \
        const bool  act   = (tt < EXP_EPS) & (e4 < (bn));                      \
        const float dist  = __logf(tt);                                        \
        const float delta = act ? (EPS_F - dist) : 0.0f;                       \
        eacc = fmaf(delta, delta, eacc);                                       \
        const float factor = (-(A_F / NUMNEG_F)) * delta *                     \
                             __builtin_amdgcn_rcpf(sq + 1e-9f);                \
        const unsigned long long ball = __ballot(act);                         \
        _Pragma("unroll")                                                      \
        for (int k = 0; k < BATCH; k++) {                                      \
            if ((ball >> (4 * k)) & 1ull) {                                    \
                const float fk = __uint_as_float(                              \
                    __builtin_amdgcn_readlane(__float_as_uint(factor), 4 * k));\
                unsafeAtomicAdd(&grad[(size_t)(vs)[k] * 64 + lane], fk * (xuj));\
                (gacc) = fmaf(fk, (xv)[k], (gacc));                            \
            }                                                                  \
        }                                                                      \
    } while (0)

// ---- K4: node kernel (R3 structure) over exact CSR adjacency ----
__global__ __launch_bounds__(256) void node_kernel(
    const float* __restrict__ x,
    const int* __restrict__ meta,
    const int* __restrict__ adj,
    float* __restrict__ out,          // out[0]=energy, out+1 = grad
    float* __restrict__ block_energy,
    int N)
{
    const int lane = threadIdx.x & 63;
    const int wib  = threadIdx.x >> 6;
    const int wave = (blockIdx.x * blockDim.x + threadIdx.x) >> 6;
    const int nwaves = (gridDim.x * blockDim.x) >> 6;
    const float sign = (lane == 0) ? -1.0f : 1.0f;   // Minkowski J
    float* __restrict__ grad = out + 1;

    const bool m32 = (lane & 32) != 0;
    const bool m16 = (lane & 16) != 0;
    const bool m8  = (lane & 8)  != 0;
    const bool m4  = (lane & 4)  != 0;
    const int  e4  = lane >> 2;

    float eacc = 0.0f;   // one-sided, 4x lane-replicated -> *0.25 at the end

    // prefetch first node's meta + adjacency (adj padded by 64 ints)
    int u = wave;
    int mu = 0, myv = 0;
    if (u < N) {
        mu  = meta[u];
        myv = adj[(mu & 0xFFFFF) + lane];
    }

    while (u < N) {
        const int deg  = mu >> 20;
        const int base = mu & 0xFFFFF;
        const int myv_c = myv;
        const float xuj = x[(size_t)u * 64 + lane] * sign;  // xu * J

        // prefetch next node (overlaps with this node's gathers/compute)
        const int un = u + nwaves;
        if (un < N) {
            mu  = meta[un];
            myv = adj[(mu & 0xFFFFF) + lane];
        }

        float gacc = 0.0f;
        const int deg_c = min(deg, 64);
        for (int k0 = 0; k0 < deg_c; k0 += BATCH) {
            const int bn = min(BATCH, deg_c - k0);
            int vs[BATCH]; float xv[BATCH];
            #pragma unroll
            for (int k = 0; k < BATCH; k++) {
                if (k < bn) {
                    vs[k] = __builtin_amdgcn_readlane(myv_c, k0 + k);
                    xv[k] = x[(size_t)vs[k] * 64 + lane];
                } else { vs[k] = 0; xv[k] = 0.0f; }
            }
            PROCESS_BATCH(xuj, vs, xv, bn, gacc);
        }
        // deg > 64 safety path (never taken at deg ~ Poisson(10); exact CSR)
        for (int k0 = 64; k0 < deg; k0 += BATCH) {
            const int bn = min(BATCH, deg - k0);
            int vs[BATCH]; float xv[BATCH];
            #pragma unroll
            for (int k = 0; k < BATCH; k++) {
                if (k < bn) {
                    vs[k] = adj[base + k0 + k];   // wave-uniform scalar loads
                    xv[k] = x[(size_t)vs[k] * 64 + lane];
                } else { vs[k] = 0; xv[k] = 0.0f; }
            }
            PROCESS_BATCH(xuj, vs, xv, bn, gacc);
        }

        if (deg > 0)
            unsafeAtomicAdd(&grad[(size_t)u * 64 + lane], gacc * sign);
        u = un;
    }

    // wave-reduce energy (each edge counted on 4 lanes -> *0.25)
    #pragma unroll
    for (int off = 32; off >= 1; off >>= 1) eacc += __shfl_xor(eacc, off, 64);
    __shared__ float se[4];
    if (lane == 0) se[wib] = eacc * 0.25f;
    __syncthreads();
    if (threadIdx.x == 0)
        block_energy[blockIdx.x] = se[0] + se[1] + se[2] + se[3];
}

// ---- K5: final energy reduce ----
__global__ __launch_bounds__(256) void energy_reduce_kernel(
    const float* __restrict__ block_energy, float* __restrict__ out, int n)
{
    const int lane = threadIdx.x & 63;
    const int wib  = threadIdx.x >> 6;
    float s = 0.0f;
    for (int i = threadIdx.x; i < n; i += 256) s += block_energy[i];
    #pragma unroll
    for (int off = 32; off >= 1; off >>= 1) s += __shfl_xor(s, off, 64);
    __shared__ float se[4];
    if (lane == 0) se[wib] = s;
    __syncthreads();
    if (threadIdx.x == 0)
        out[0] = (se[0] + se[1] + se[2] + se[3]) * (0.5f * A_F / NUMNEG_F);
}

extern "C" void kernel_launch(void* const* d_in, const int* in_sizes, int n_in,
                              void* d_out, int out_size, void* d_ws, size_t ws_size,
                              hipStream_t stream) {
    const float* x     = (const float*)d_in[0];
    const int*   u_idx = (const int*)d_in[1];
    const int*   v_idx = (const int*)d_in[2];
    float* out = (float*)d_out;
    const int E = in_sizes[1];
    const int N = in_sizes[0] / 64;
    const int NB = (N + 255) / 256;   // scan chunks

    // ws layout
    char* ws = (char*)d_ws;
    int*   counts       = (int*)(ws);                        // N ints   (400 KB)
    int*   slot         = (int*)(ws + (1u << 20));           // E ints   (4 MB)
    int*   partials     = (int*)(ws + (11u << 19));          // NB ints  @5.5 MB
    int*   meta         = (int*)(ws + (6u << 20));           // N ints   @6 MB
    int*   adj          = (int*)(ws + (8u << 20));           // E+64 ints @8 MB
    float* block_energy = (float*)(ws + (13u << 20));        // NBLOCKS  @13 MB

    hipMemsetAsync(counts, 0, (size_t)N * sizeof(int), stream);

    // K1: zero d_out + histogram + per-edge slot
    hist_kernel<<<4096, 256, 0, stream>>>(u_idx, counts, slot, out, out_size, E);
    // K2: exclusive prefix sum -> packed meta (offset | deg<<20)
    scan_partial_kernel<<<NB, 256, 0, stream>>>(counts, partials, N);
    scan_bases_kernel<<<1, 64, 0, stream>>>(partials, NB);
    scan_meta_kernel<<<NB, 256, 0, stream>>>(counts, partials, meta, N);
    // K3: atomic-free CSR scatter
    scatter_kernel<<<4096, 256, 0, stream>>>(u_idx, v_idx, slot, meta, adj, E);
    // K4: node pass
    node_kernel<<<NBLOCKS, 256, 0, stream>>>(x, meta, adj, out, block_energy, N);
    // K5: energy reduce
    energy_reduce_kernel<<<1, 256, 0, stream>>>(block_energy, out, NBLOCKS);
}